// Round 1
// baseline (232.002 us; speedup 1.0000x reference)
//
#include <hip/hip_runtime.h>

// LIF forward recurrence:
//   mem0 = x[0]; spike0 = (mem0 > 0.5)
//   mem_t = mem_{t-1} * 0.25 * (1 - spike_{t-1}) + x_t ; spike_t = (mem_t > 0.5)
// Output: spikes [T, B, D] float32.
// Purely element-wise in (b,d), sequential only in t -> one thread per 4
// consecutive d values, recurrence state in registers, float4 I/O.

constexpr int   T_STEPS = 32;
constexpr float THRESH  = 0.5f;
constexpr float DECAY   = 0.25f;

__global__ __launch_bounds__(256) void lif_fwd_kernel(
    const float4* __restrict__ x,   // [T, n4] as float4
    float4* __restrict__ out,       // [T, n4] as float4
    int n4)                         // (B*D)/4 float4 groups per timestep
{
    int i = blockIdx.x * 256 + threadIdx.x;
    if (i >= n4) return;

    // t = 0: mem = x[0], spike = (mem > thresh)
    float4 mem = x[i];
    float4 s;
    s.x = mem.x > THRESH ? 1.0f : 0.0f;
    s.y = mem.y > THRESH ? 1.0f : 0.0f;
    s.z = mem.z > THRESH ? 1.0f : 0.0f;
    s.w = mem.w > THRESH ? 1.0f : 0.0f;
    out[i] = s;

#pragma unroll
    for (int t = 1; t < T_STEPS; ++t) {
        float4 xv = x[t * n4 + i];  // independent of recurrence -> compiler can prefetch
        mem.x = mem.x * (DECAY * (1.0f - s.x)) + xv.x;
        mem.y = mem.y * (DECAY * (1.0f - s.y)) + xv.y;
        mem.z = mem.z * (DECAY * (1.0f - s.z)) + xv.z;
        mem.w = mem.w * (DECAY * (1.0f - s.w)) + xv.w;
        s.x = mem.x > THRESH ? 1.0f : 0.0f;
        s.y = mem.y > THRESH ? 1.0f : 0.0f;
        s.z = mem.z > THRESH ? 1.0f : 0.0f;
        s.w = mem.w > THRESH ? 1.0f : 0.0f;
        out[t * n4 + i] = s;
    }
}

extern "C" void kernel_launch(void* const* d_in, const int* in_sizes, int n_in,
                              void* d_out, int out_size, void* d_ws, size_t ws_size,
                              hipStream_t stream) {
    const float* x = (const float*)d_in[0];
    float* out = (float*)d_out;

    const int total = in_sizes[0];        // T * B * D = 33_554_432
    const int n     = total / T_STEPS;    // B * D     = 1_048_576
    const int n4    = n / 4;              // 262_144 float4 groups

    const int block = 256;
    const int grid  = (n4 + block - 1) / block;  // 1024 blocks

    lif_fwd_kernel<<<grid, block, 0, stream>>>(
        reinterpret_cast<const float4*>(x),
        reinterpret_cast<float4*>(out),
        n4);
}

// Round 2
// 230.920 us; speedup vs baseline: 1.0047x; 1.0047x over previous
//
#include <hip/hip_runtime.h>

// LIF forward recurrence:
//   mem0 = x[0]; spike0 = (mem0 > 0.5)
//   mem_t = mem_{t-1} * 0.25 * (1 - spike_{t-1}) + x_t ; spike_t = (mem_t > 0.5)
// Output: spikes [T, B, D] float32.
//
// Element-wise in (b,d), sequential in t. One thread per 4 consecutive d.
// Round 1 showed 2.5 TB/s (latency-bound, VGPR=32, ~2 loads in flight).
// Round 2: explicit double-buffered software pipeline — 4 chunks of 8
// timesteps, chunk c+1's 8 float4 loads issued before computing chunk c,
// keeping 8-16 loads in flight per thread. Non-temporal stores keep the
// write-once output from evicting warm x lines in L2/L3.

constexpr int   T_STEPS = 32;
constexpr int   CHUNK   = 8;
constexpr float THRESH  = 0.5f;
constexpr float DECAY   = 0.25f;

typedef float v4f __attribute__((ext_vector_type(4)));

__device__ __forceinline__ void load_chunk(float4* buf, const float4* __restrict__ xp,
                                           int t0, int n4) {
#pragma unroll
    for (int k = 0; k < CHUNK; ++k)
        buf[k] = xp[(t0 + k) * n4];
}

template <int T0>
__device__ __forceinline__ void compute_chunk(const float4* buf, float4& mem, float4& s,
                                              float4* __restrict__ op, int n4) {
#pragma unroll
    for (int k = 0; k < CHUNK; ++k) {
        float4 v = buf[k];
        if (T0 + k == 0) {
            mem = v;  // mem0 = x[0]
        } else {
            mem.x = mem.x * (DECAY * (1.0f - s.x)) + v.x;
            mem.y = mem.y * (DECAY * (1.0f - s.y)) + v.y;
            mem.z = mem.z * (DECAY * (1.0f - s.z)) + v.z;
            mem.w = mem.w * (DECAY * (1.0f - s.w)) + v.w;
        }
        s.x = mem.x > THRESH ? 1.0f : 0.0f;
        s.y = mem.y > THRESH ? 1.0f : 0.0f;
        s.z = mem.z > THRESH ? 1.0f : 0.0f;
        s.w = mem.w > THRESH ? 1.0f : 0.0f;
        v4f sv = {s.x, s.y, s.z, s.w};
        __builtin_nontemporal_store(sv, (v4f*)(op + (T0 + k) * n4));
    }
}

__global__ __launch_bounds__(256) void lif_fwd_kernel(
    const float4* __restrict__ x,   // [T, n4]
    float4* __restrict__ out,       // [T, n4]
    int n4)
{
    int i = blockIdx.x * 256 + threadIdx.x;
    if (i >= n4) return;

    const float4* xp = x + i;
    float4*       op = out + i;

    float4 bufA[CHUNK], bufB[CHUNK];
    float4 mem, s;

    // Pipeline: A(0-7), B(8-15) in flight; compute A; load A(16-23);
    // compute B; load B(24-31); compute A; compute B.
    load_chunk(bufA, xp, 0, n4);
    load_chunk(bufB, xp, 8, n4);
    compute_chunk<0>(bufA, mem, s, op, n4);
    load_chunk(bufA, xp, 16, n4);
    compute_chunk<8>(bufB, mem, s, op, n4);
    load_chunk(bufB, xp, 24, n4);
    compute_chunk<16>(bufA, mem, s, op, n4);
    compute_chunk<24>(bufB, mem, s, op, n4);
}

extern "C" void kernel_launch(void* const* d_in, const int* in_sizes, int n_in,
                              void* d_out, int out_size, void* d_ws, size_t ws_size,
                              hipStream_t stream) {
    const float* x = (const float*)d_in[0];
    float* out = (float*)d_out;

    const int total = in_sizes[0];        // T * B * D = 33_554_432
    const int n     = total / T_STEPS;    // B * D     = 1_048_576
    const int n4    = n / 4;              // 262_144 float4 groups

    const int block = 256;
    const int grid  = (n4 + block - 1) / block;  // 1024 blocks

    lif_fwd_kernel<<<grid, block, 0, stream>>>(
        reinterpret_cast<const float4*>(x),
        reinterpret_cast<float4*>(out),
        n4);
}